// Round 4
// baseline (493.230 us; speedup 1.0000x reference)
//
#include <hip/hip_runtime.h>
#include <stdint.h>

// N=16, M=4, D=32, K=256, H=64, W=64 ; P = 262144 pixels
// outputs (concat, read back as f32): sample (P*256), code (P, as float), logit (P*256)

#define TINY_F 1.17549435082228750797e-38f

// XLA:CPU vectorized log (GenerateVF32Log / Eigen plog), UNFUSED mul+add.
// Bit-exactness validated round 2 (code absmax == 0). DO NOT TOUCH.
__device__ __forceinline__ float plog_xla(float xin) {
  #pragma clang fp contract(off)
  uint32_t ix = __float_as_uint(xin);
  int e_i = (int)(ix >> 23) - 126;
  float x = __uint_as_float((ix & 0x007FFFFFu) | 0x3F000000u);
  float e = (float)e_i;
  bool lt = x < 0.707106781186547524f;
  float tmp = lt ? x : 0.0f;
  x = x - 1.0f;
  e = e - (lt ? 1.0f : 0.0f);
  x = x + tmp;
  float z  = x * x;
  float x3 = z * x;
  float y  =  7.0376836292e-2f * x + (-1.1514610310e-1f);
  float y1 = -1.2420140846e-1f * x +   1.4249322787e-1f;
  float y2 =  2.0000714765e-1f * x + (-2.4999993993e-1f);
  y  = y  * x +   1.1676998740e-1f;
  y1 = y1 * x + (-1.6668057665e-1f);
  y2 = y2 * x +   3.3333331174e-1f;
  y  = y * x3 + y1;
  y  = y * x3 + y2;
  y  = y * x3;
  y  = y + e * (-2.12194440e-4f);
  x  = x - 0.5f * z;
  x  = x + y;
  x  = x + e * 0.693359375f;
  return x;
}

__device__ __forceinline__ void threefry2x32(uint32_t k0, uint32_t k1,
                                             uint32_t x0, uint32_t x1,
                                             uint32_t& o0, uint32_t& o1) {
  uint32_t ks2 = k0 ^ k1 ^ 0x1BD11BDAu;
  x0 += k0; x1 += k1;
#define TF_RND(r) { x0 += x1; x1 = (x1 << (r)) | (x1 >> (32 - (r))); x1 ^= x0; }
  TF_RND(13) TF_RND(15) TF_RND(26) TF_RND(6)
  x0 += k1; x1 += ks2 + 1u;
  TF_RND(17) TF_RND(29) TF_RND(16) TF_RND(24)
  x0 += ks2; x1 += k0 + 2u;
  TF_RND(13) TF_RND(15) TF_RND(26) TF_RND(6)
  x0 += k0; x1 += k1 + 3u;
  TF_RND(17) TF_RND(29) TF_RND(16) TF_RND(24)
  x0 += k1; x1 += ks2 + 4u;
  TF_RND(13) TF_RND(15) TF_RND(26) TF_RND(6)
  x0 += ks2; x1 += k0 + 5u;
#undef TF_RND
  o0 = x0; o1 = x1;
}

__device__ __forceinline__ float gumbel_from_bits(uint32_t bits) {
  uint32_t mant = bits >> 9;
  float f = __uint_as_float(0x3F800000u | mant) - 1.0f;
  float u = mant ? f : TINY_F;
  float t = -plog_xla(u);
  return -plog_xla(t);
}

constexpr int KK = 256;
constexpr int DD = 32;

__global__ __launch_bounds__(256, 4)
void mcq_kernel(const float* __restrict__ x, const float* __restrict__ cb,
                float* __restrict__ sample, float* __restrict__ code,
                float* __restrict__ logit) {
  __shared__ int s_wb[256];

  const int t  = threadIdx.x;
  const int b  = blockIdx.x;             // 1024 blocks
  const int nm = b >> 4;                 // n*4+m, 0..63
  const int m  = nm & 3;
  const int hw = ((b & 15) << 8) + t;    // 0..4095
  const int gp = (nm << 12) + hw;        // global pixel index (n,m,h,w order)

  // x[d] for this pixel -> VGPRs (coalesced across threads for each d)
  const float* xp = x + ((size_t)(nm * 32)) * 4096 + hw;
  float xv[DD];
  #pragma unroll
  for (int d = 0; d < DD; d++) xv[d] = xp[(size_t)d * 4096];

  // x2: UNFUSED ascending chain (XLA reduce) — bit-identical to round 2
  float x2;
  {
    #pragma clang fp contract(off)
    float a = 0.0f;
    #pragma unroll
    for (int d = 0; d < DD; d++) a = a + xv[d] * xv[d];
    x2 = a;
  }

  const float* cbm = cb + (size_t)m * (KK * DD);   // wave-uniform
  float* lrow = logit + ((size_t)gp << 8);

  float best = -__builtin_inff();
  int wb = 0;

  for (int kc = 0; kc < KK; kc += 16) {
    float L[16];
    #pragma unroll
    for (int kk = 0; kk < 16; kk++) {
      const int k = kc + kk;
      const float* cp = cbm + k * DD;    // uniform -> scalar loads (SMEM)
      float cr[DD];
      #pragma unroll
      for (int j = 0; j < 8; j++) {
        float4 q = ((const float4*)cp)[j];
        cr[4*j+0] = q.x; cr[4*j+1] = q.y; cr[4*j+2] = q.z; cr[4*j+3] = q.w;
      }
      // c2: UNFUSED ascending chain (uniform arithmetic, cheap)
      float c2;
      {
        #pragma clang fp contract(off)
        float a = 0.0f;
        #pragma unroll
        for (int d = 0; d < DD; d++) a = a + cr[d] * cr[d];
        c2 = a;
      }
      // inter: FUSED ascending fma chain
      float inter = 0.0f;
      #pragma unroll
      for (int d = 0; d < DD; d++)
        inter = __builtin_fmaf(xv[d], cr[d], inter);

      float dist = (x2 + c2) - 2.0f * inter;       // 2*inter exact
      float Lk = plog_xla(dist);
      L[kk] = Lk;

      // partitionable threefry: counter=(0, gp*256+k), bits = v0^v1
      uint32_t l = ((uint32_t)gp << 8) | (uint32_t)k;
      uint32_t v0, v1;
      threefry2x32(0u, 42u, 0u, l, v0, v1);
      float g = gumbel_from_bits(v0 ^ v1);
      float phi = g + Lk;

      if (phi > best) { best = phi; wb = k; }      // strict > == first occurrence
    }
    // 4 x dwordx4 back-to-back: each 64B line fully covered
    float4* dst = (float4*)(lrow + kc);
    #pragma unroll
    for (int q = 0; q < 4; q++)
      dst[q] = make_float4(L[4*q+0], L[4*q+1], L[4*q+2], L[4*q+3]);
  }

  code[gp] = (float)wb;
  s_wb[t] = wb;
  __syncthreads();

  // cooperative coalesced one-hot: wave wv writes rows [wv*64, wv*64+64)
  const int lane = t & 63, wv = t >> 6;
  const int pbase = (nm << 12) + ((b & 15) << 8);
  const int k0 = lane << 2;                        // this lane's 4 k slots
  for (int r = wv * 64; r < (wv + 1) * 64; r++) {
    const int w = s_wb[r];                         // broadcast read
    float4 v;
    v.x = (w == k0 + 0) ? 1.0f : 0.0f;
    v.y = (w == k0 + 1) ? 1.0f : 0.0f;
    v.z = (w == k0 + 2) ? 1.0f : 0.0f;
    v.w = (w == k0 + 3) ? 1.0f : 0.0f;
    ((float4*)(sample + (((size_t)(pbase + r)) << 8)))[lane] = v;
  }
}

extern "C" void kernel_launch(void* const* d_in, const int* in_sizes, int n_in,
                              void* d_out, int out_size, void* d_ws, size_t ws_size,
                              hipStream_t stream) {
  const float* x  = (const float*)d_in[0];
  const float* cb = (const float*)d_in[1];

  float* out_f  = (float*)d_out;
  float* sample = out_f;                       // 67108864
  float* code   = out_f + 67108864;            // 262144 (as float)
  float* logit  = out_f + 67108864 + 262144;   // 67108864

  mcq_kernel<<<1024, 256, 0, stream>>>(x, cb, sample, code, logit);
}

// Round 6
// 485.873 us; speedup vs baseline: 1.0151x; 1.0151x over previous
//
#include <hip/hip_runtime.h>
#include <stdint.h>

// N=16, M=4, D=32, K=256, H=64, W=64 ; P = 262144 pixels
// outputs (concat, read back as f32): sample (P*256), code (P, as float), logit (P*256)

#define TINY_F 1.17549435082228750797e-38f

// XLA:CPU vectorized log (GenerateVF32Log / Eigen plog), UNFUSED mul+add.
// Bit-exactness validated round 2 (code absmax == 0). DO NOT TOUCH.
__device__ __forceinline__ float plog_xla(float xin) {
  #pragma clang fp contract(off)
  uint32_t ix = __float_as_uint(xin);
  int e_i = (int)(ix >> 23) - 126;
  float x = __uint_as_float((ix & 0x007FFFFFu) | 0x3F000000u);
  float e = (float)e_i;
  bool lt = x < 0.707106781186547524f;
  float tmp = lt ? x : 0.0f;
  x = x - 1.0f;
  e = e - (lt ? 1.0f : 0.0f);
  x = x + tmp;
  float z  = x * x;
  float x3 = z * x;
  float y  =  7.0376836292e-2f * x + (-1.1514610310e-1f);
  float y1 = -1.2420140846e-1f * x +   1.4249322787e-1f;
  float y2 =  2.0000714765e-1f * x + (-2.4999993993e-1f);
  y  = y  * x +   1.1676998740e-1f;
  y1 = y1 * x + (-1.6668057665e-1f);
  y2 = y2 * x +   3.3333331174e-1f;
  y  = y * x3 + y1;
  y  = y * x3 + y2;
  y  = y * x3;
  y  = y + e * (-2.12194440e-4f);
  x  = x - 0.5f * z;
  x  = x + y;
  x  = x + e * 0.693359375f;
  return x;
}

// UNFUSED ascending square-sum (XLA reduce order). Pragma at body start.
__device__ __forceinline__ float sumsq_unfused(const float* v) {
  #pragma clang fp contract(off)
  float a = 0.0f;
  #pragma unroll
  for (int d = 0; d < 32; d++) a = a + v[d] * v[d];
  return a;
}

__device__ __forceinline__ void threefry2x32(uint32_t k0, uint32_t k1,
                                             uint32_t x0, uint32_t x1,
                                             uint32_t& o0, uint32_t& o1) {
  uint32_t ks2 = k0 ^ k1 ^ 0x1BD11BDAu;
  x0 += k0; x1 += k1;
#define TF_RND(r) { x0 += x1; x1 = (x1 << (r)) | (x1 >> (32 - (r))); x1 ^= x0; }
  TF_RND(13) TF_RND(15) TF_RND(26) TF_RND(6)
  x0 += k1; x1 += ks2 + 1u;
  TF_RND(17) TF_RND(29) TF_RND(16) TF_RND(24)
  x0 += ks2; x1 += k0 + 2u;
  TF_RND(13) TF_RND(15) TF_RND(26) TF_RND(6)
  x0 += k0; x1 += k1 + 3u;
  TF_RND(17) TF_RND(29) TF_RND(16) TF_RND(24)
  x0 += k1; x1 += ks2 + 4u;
  TF_RND(13) TF_RND(15) TF_RND(26) TF_RND(6)
  x0 += ks2; x1 += k0 + 5u;
#undef TF_RND
  o0 = x0; o1 = x1;
}

__device__ __forceinline__ float gumbel_from_bits(uint32_t bits) {
  uint32_t mant = bits >> 9;
  float f = __uint_as_float(0x3F800000u | mant) - 1.0f;
  float u = mant ? f : TINY_F;
  float t = -plog_xla(u);
  return -plog_xla(t);
}

constexpr int KK = 256;
constexpr int DD = 32;

__global__ __launch_bounds__(256, 4)
void mcq_kernel(const float* __restrict__ x, const float* __restrict__ cb,
                float* __restrict__ sample, float* __restrict__ code,
                float* __restrict__ logit) {
  __shared__ __align__(16) float s_cb[KK * DD];   // 32 KB, 128B rows (16B aligned)
  __shared__ __align__(16) float s_c2[KK];        // 1 KB
  __shared__ int s_wb[256];                       // 1 KB

  const int t  = threadIdx.x;
  const int b  = blockIdx.x;             // 1024 blocks
  const int nm = b >> 4;                 // n*4+m
  const int m  = nm & 3;
  const int hw = ((b & 15) << 8) + t;
  const int gp = (nm << 12) + hw;        // global pixel index

  const float* cbm = cb + (size_t)m * (KK * DD);

  // stage codebook -> LDS (coalesced float4, 8 per thread)
  {
    const float4* src = (const float4*)cbm;
    float4* dst = (float4*)s_cb;
    #pragma unroll
    for (int i = 0; i < 8; i++)
      dst[t + 256 * i] = src[t + 256 * i];
  }

  // x[d] -> VGPRs (coalesced across threads per d)
  const float* xp = x + ((size_t)(nm * 32)) * 4096 + hw;
  float xv[DD];
  #pragma unroll
  for (int d = 0; d < DD; d++) xv[d] = xp[(size_t)d * 4096];

  const float x2 = sumsq_unfused(xv);

  // c2 for row k=t, once per block, from global (L2-hot) — UNFUSED chain (validated)
  {
    const float4* rp = (const float4*)(cbm + t * DD);
    float cr[DD];
    #pragma unroll
    for (int j = 0; j < 8; j++) {
      float4 q = rp[j];
      cr[4*j+0] = q.x; cr[4*j+1] = q.y; cr[4*j+2] = q.z; cr[4*j+3] = q.w;
    }
    s_c2[t] = sumsq_unfused(cr);
  }
  __syncthreads();

  float* lrow = logit + ((size_t)gp << 8);
  float best = -__builtin_inff();
  int wb = 0;
  const uint32_t lbase = (uint32_t)gp << 8;

  #pragma unroll 1
  for (int kc = 0; kc < KK; kc += 4) {
    const float4 c2q = *(const float4*)(s_c2 + kc);   // broadcast b128
    float L[4];
    #pragma unroll
    for (int kk = 0; kk < 4; kk += 2) {
      const int k0 = kc + kk;
      const float4* r0 = (const float4*)(s_cb + (size_t)k0 * DD);
      const float4* r1 = (const float4*)(s_cb + (size_t)(k0 + 1) * DD);

      // two independent FUSED ascending fma chains (validated order)
      float i0 = 0.0f, i1 = 0.0f;
      #pragma unroll
      for (int j = 0; j < 8; j++) {
        float4 q0 = r0[j];
        float4 q1 = r1[j];
        i0 = __builtin_fmaf(xv[4*j+0], q0.x, i0);
        i1 = __builtin_fmaf(xv[4*j+0], q1.x, i1);
        i0 = __builtin_fmaf(xv[4*j+1], q0.y, i0);
        i1 = __builtin_fmaf(xv[4*j+1], q1.y, i1);
        i0 = __builtin_fmaf(xv[4*j+2], q0.z, i0);
        i1 = __builtin_fmaf(xv[4*j+2], q1.z, i1);
        i0 = __builtin_fmaf(xv[4*j+3], q0.w, i0);
        i1 = __builtin_fmaf(xv[4*j+3], q1.w, i1);
      }

      const float c20 = (kk == 0) ? c2q.x : c2q.z;
      const float c21 = (kk == 0) ? c2q.y : c2q.w;
      float d0 = (x2 + c20) - 2.0f * i0;   // 2*inter exact
      float d1 = (x2 + c21) - 2.0f * i1;
      float L0 = plog_xla(d0);
      float L1 = plog_xla(d1);

      // partitionable threefry: counter=(0, gp*256+k), bits = v0^v1 (validated)
      uint32_t v0, v1, w0, w1;
      threefry2x32(0u, 42u, 0u, lbase | (uint32_t)k0, v0, v1);
      threefry2x32(0u, 42u, 0u, lbase | (uint32_t)(k0 + 1), w0, w1);
      float g0 = gumbel_from_bits(v0 ^ v1);
      float g1 = gumbel_from_bits(w0 ^ w1);
      float p0 = g0 + L0;
      float p1 = g1 + L1;

      if (p0 > best) { best = p0; wb = k0; }       // ascending strict > ==
      if (p1 > best) { best = p1; wb = k0 + 1; }   // first-occurrence ties
      L[kk] = L0; L[kk + 1] = L1;
    }
    *(float4*)(lrow + kc) = make_float4(L[0], L[1], L[2], L[3]);
  }

  code[gp] = (float)wb;
  s_wb[t] = wb;
  __syncthreads();

  // cooperative coalesced one-hot sample write
  const int lane = t & 63, wv = t >> 6;
  const int pbase = (nm << 12) + ((b & 15) << 8);
  const int k0 = lane << 2;
  for (int r = wv * 64; r < (wv + 1) * 64; r++) {
    const int w = s_wb[r];
    float4 v;
    v.x = (w == k0 + 0) ? 1.0f : 0.0f;
    v.y = (w == k0 + 1) ? 1.0f : 0.0f;
    v.z = (w == k0 + 2) ? 1.0f : 0.0f;
    v.w = (w == k0 + 3) ? 1.0f : 0.0f;
    ((float4*)(sample + (((size_t)(pbase + r)) << 8)))[lane] = v;
  }
}

extern "C" void kernel_launch(void* const* d_in, const int* in_sizes, int n_in,
                              void* d_out, int out_size, void* d_ws, size_t ws_size,
                              hipStream_t stream) {
  const float* x  = (const float*)d_in[0];
  const float* cb = (const float*)d_in[1];

  float* out_f  = (float*)d_out;
  float* sample = out_f;                       // 67108864
  float* code   = out_f + 67108864;            // 262144 (as float)
  float* logit  = out_f + 67108864 + 262144;   // 67108864

  mcq_kernel<<<1024, 256, 0, stream>>>(x, cb, sample, code, logit);
}